// Round 1
// baseline (163.199 us; speedup 1.0000x reference)
//
#include <hip/hip_runtime.h>
#include <math.h>

#define K_INST 256
#define ATTRACTION_W 1.0f
#define REPULSION_W 1.0f
#define BETA_POS_W 1.0f
#define BETA_NEG_W 0.5f

__device__ inline float softplusf(float x) {
    // numerically stable: max(x,0) + log1p(exp(-|x|))
    return fmaxf(x, 0.f) + log1pf(expf(-fabsf(x)));
}

__device__ inline float waveReduceSumF(float v) {
    for (int o = 32; o; o >>= 1) v += __shfl_xor(v, o);
    return v;
}
__device__ inline int waveReduceSumI(int v) {
    for (int o = 32; o; o >>= 1) v += __shfl_xor(v, o);
    return v;
}

// ---------------- workspace layout (bytes) ----------------
// [0]          first_cp   : B*K int
// [OFF_SEGS]   seg_sum    : B*K float
// [OFF_SEGC]   seg_cnt    : B*K int
// [OFF_POS]    pos_sum    : B float
// [OFF_NEG]    neg_sum    : B float
// [OFF_REP]    rep_sum    : B float
// [OFF_CPV]    cpv_cnt    : B int
// [OFF_NON]    noncp_cnt  : B int
// [OFF_VAL]    valid_cnt  : B int
// [OFF_CPEMB]  cp_emb     : B*K*D float

__global__ void init_kernel(int* first_cp, float* seg_sum, int* seg_cnt,
                            float* pos_sum, float* neg_sum, float* rep_sum,
                            int* cpv_cnt, int* noncp_cnt, int* valid_cnt,
                            int N, int B) {
    int idx = blockIdx.x * blockDim.x + threadIdx.x;
    if (idx < B * K_INST) {
        first_cp[idx] = N;
        seg_sum[idx] = 0.f;
        seg_cnt[idx] = 0;
    }
    if (idx < B) {
        pos_sum[idx] = 0.f; neg_sum[idx] = 0.f; rep_sum[idx] = 0.f;
        cpv_cnt[idx] = 0; noncp_cnt[idx] = 0; valid_cnt[idx] = 0;
    }
}

// one thread per point: BCE sums, counts, first_cp atomicMin
__global__ void stats_kernel(const float* __restrict__ beta,
                             const int* __restrict__ sid,
                             const int* __restrict__ is_cp,
                             int* first_cp,
                             float* pos_sum, float* neg_sum,
                             int* cpv_cnt, int* noncp_cnt, int* valid_cnt,
                             int N) {
    int b = blockIdx.y;
    int i = blockIdx.x * blockDim.x + threadIdx.x;
    float pos = 0.f, neg = 0.f;
    int c_cpv = 0, c_non = 0, c_val = 0;
    if (i < N) {
        size_t gi = (size_t)b * N + i;
        int s = sid[gi];
        int cp = is_cp[gi];
        bool valid = (s >= 0);
        bool cpv = cp && valid;
        if (cpv) {
            float x = beta[gi];
            pos = softplusf(-x);
            c_cpv = 1;
            atomicMin(&first_cp[b * K_INST + s], i);
        }
        if (!cp) {
            float x = beta[gi];
            neg = softplusf(x);
            c_non = 1;
        }
        c_val = valid ? 1 : 0;
    }
    // block reduce (256 threads = 4 waves)
    __shared__ float sf[2][4];
    __shared__ int si[3][4];
    pos = waveReduceSumF(pos);
    neg = waveReduceSumF(neg);
    c_cpv = waveReduceSumI(c_cpv);
    c_non = waveReduceSumI(c_non);
    c_val = waveReduceSumI(c_val);
    int wave = threadIdx.x >> 6, lane = threadIdx.x & 63;
    if (lane == 0) {
        sf[0][wave] = pos; sf[1][wave] = neg;
        si[0][wave] = c_cpv; si[1][wave] = c_non; si[2][wave] = c_val;
    }
    __syncthreads();
    if (threadIdx.x == 0) {
        float p = sf[0][0] + sf[0][1] + sf[0][2] + sf[0][3];
        float n = sf[1][0] + sf[1][1] + sf[1][2] + sf[1][3];
        int a = si[0][0] + si[0][1] + si[0][2] + si[0][3];
        int c = si[1][0] + si[1][1] + si[1][2] + si[1][3];
        int v = si[2][0] + si[2][1] + si[2][2] + si[2][3];
        if (p != 0.f) atomicAdd(&pos_sum[b], p);
        if (n != 0.f) atomicAdd(&neg_sum[b], n);
        if (a) atomicAdd(&cpv_cnt[b], a);
        if (c) atomicAdd(&noncp_cnt[b], c);
        if (v) atomicAdd(&valid_cnt[b], v);
    }
}

// gather cp_emb[b][k] = embed[b][min(first_cp,N-1)]  (64 threads per (b,k))
__global__ void gather_kernel(const float* __restrict__ embed,
                              const int* __restrict__ first_cp,
                              float* __restrict__ cp_emb, int N) {
    int b = blockIdx.y;
    int k = blockIdx.x;
    int src = first_cp[b * K_INST + k];
    if (src >= N) src = N - 1;
    const float4* s = (const float4*)(embed + ((size_t)b * N + src) * 256);
    float4* d = (float4*)(cp_emb + ((size_t)b * K_INST + k) * 256);
    d[threadIdx.x] = s[threadIdx.x];
}

// attraction: one wave (64 lanes) per point, float4 loads (64*4 = 256 dims)
__global__ void attraction_kernel(const float* __restrict__ embed,
                                  const int* __restrict__ sid,
                                  const int* __restrict__ first_cp,
                                  const float* __restrict__ cp_emb,
                                  float* seg_sum, int* seg_cnt,
                                  int N, int blocks_per_batch) {
    int b = blockIdx.y;
    __shared__ float s_sum[K_INST];
    __shared__ int s_cnt[K_INST];
    for (int k = threadIdx.x; k < K_INST; k += blockDim.x) { s_sum[k] = 0.f; s_cnt[k] = 0; }
    __syncthreads();

    int wave = threadIdx.x >> 6;
    int lane = threadIdx.x & 63;
    int waves_per_batch = blocks_per_batch * 4;
    int wslot = blockIdx.x * 4 + wave;

    const float* embB = embed + (size_t)b * N * 256;
    const float* cpB  = cp_emb + (size_t)b * K_INST * 256;
    const int* sidB   = sid + (size_t)b * N;
    const int* fcB    = first_cp + b * K_INST;

    for (int i = wslot; i < N; i += waves_per_batch) {
        int s = sidB[i];               // wave-uniform (all lanes same i)
        if (s < 0) continue;
        if (fcB[s] >= N) continue;     // no CP for this instance
        float4 e = *(const float4*)(embB + (size_t)i * 256 + lane * 4);
        float4 c = *(const float4*)(cpB + (size_t)s * 256 + lane * 4);
        float d0 = e.x - c.x, d1 = e.y - c.y, d2 = e.z - c.z, d3 = e.w - c.w;
        float v = d0 * d0 + d1 * d1 + d2 * d2 + d3 * d3;
        v = waveReduceSumF(v);
        if (lane == 0) {
            atomicAdd(&s_sum[s], v);
            atomicAdd(&s_cnt[s], 1);
        }
    }
    __syncthreads();
    for (int k = threadIdx.x; k < K_INST; k += blockDim.x) {
        if (s_cnt[k]) {
            atomicAdd(&seg_sum[b * K_INST + k], s_sum[k]);
            atomicAdd(&seg_cnt[b * K_INST + k], s_cnt[k]);
        }
    }
}

// repulsion: block (b,i), thread j; sum exp(-||cp_i - cp_j||^2) over masked pairs
__global__ void repulsion_kernel(const float* __restrict__ cp_emb,
                                 const int* __restrict__ first_cp,
                                 float* rep_sum, int N) {
    int b = blockIdx.y;
    int i = blockIdx.x;
    const float* cpB = cp_emb + (size_t)b * K_INST * 256;
    __shared__ float s_row[256];
    s_row[threadIdx.x] = cpB[(size_t)i * 256 + threadIdx.x];
    __syncthreads();

    int j = threadIdx.x;
    float val = 0.f;
    bool has_i = first_cp[b * K_INST + i] < N;
    bool has_j = first_cp[b * K_INST + j] < N;
    if (has_i && has_j) {
        const float* cj = cpB + (size_t)j * 256;
        float acc = 0.f;
        for (int d = 0; d < 256; d += 4) {
            float4 v = *(const float4*)(cj + d);
            float a0 = s_row[d + 0] - v.x;
            float a1 = s_row[d + 1] - v.y;
            float a2 = s_row[d + 2] - v.z;
            float a3 = s_row[d + 3] - v.w;
            acc += a0 * a0 + a1 * a1 + a2 * a2 + a3 * a3;
        }
        val = expf(-acc);
    }
    // block reduce
    __shared__ float sf[4];
    val = waveReduceSumF(val);
    int wave = threadIdx.x >> 6, lane = threadIdx.x & 63;
    if (lane == 0) sf[wave] = val;
    __syncthreads();
    if (threadIdx.x == 0) {
        float t = sf[0] + sf[1] + sf[2] + sf[3];
        atomicAdd(&rep_sum[b], t);
    }
}

// final scalar assembly: 1 block, 256 threads
__global__ void final_kernel(const int* __restrict__ first_cp,
                             const float* __restrict__ seg_sum,
                             const int* __restrict__ seg_cnt,
                             const float* __restrict__ pos_sum,
                             const float* __restrict__ neg_sum,
                             const float* __restrict__ rep_sum,
                             const int* __restrict__ cpv_cnt,
                             const int* __restrict__ noncp_cnt,
                             const int* __restrict__ valid_cnt,
                             float* out, int N, int B) {
    __shared__ float s_att[4];
    __shared__ int s_m[4];
    float loss_sum = 0.f;
    int ok_cnt = 0;
    int wave = threadIdx.x >> 6, lane = threadIdx.x & 63;
    for (int b = 0; b < B; ++b) {
        int k = threadIdx.x;
        int fc = first_cp[b * K_INST + k];
        int has = (fc < N) ? 1 : 0;
        int cnt = seg_cnt[b * K_INST + k];
        float att = (cnt > 0) ? (seg_sum[b * K_INST + k] / (float)cnt) : 0.f;
        att = waveReduceSumF(att);
        has = waveReduceSumI(has);
        if (lane == 0) { s_att[wave] = att; s_m[wave] = has; }
        __syncthreads();
        if (threadIdx.x == 0) {
            float attraction = (s_att[0] + s_att[1] + s_att[2] + s_att[3]) * ATTRACTION_W;
            int M = s_m[0] + s_m[1] + s_m[2] + s_m[3];
            float pos = pos_sum[b] / fmaxf((float)cpv_cnt[b], 1.f);
            float neg = neg_sum[b] / fmaxf((float)noncp_cnt[b], 1.f);
            float beta_loss = BETA_POS_W * pos + BETA_NEG_W * neg;
            float rep = 0.f;
            if (M > 1) {
                float mm = (float)M * (float)M;
                rep = (rep_sum[b] / fmaxf(mm, 1.f)) * REPULSION_W;
            }
            float loss = beta_loss + attraction + rep;
            bool ok = (valid_cnt[b] > 0) && (cpv_cnt[b] > 0);
            if (ok) { loss_sum += loss; ok_cnt += 1; }
        }
        __syncthreads();
    }
    if (threadIdx.x == 0) {
        out[0] = (ok_cnt > 0) ? (loss_sum / (float)ok_cnt) : 0.f;
    }
}

extern "C" void kernel_launch(void* const* d_in, const int* in_sizes, int n_in,
                              void* d_out, int out_size, void* d_ws, size_t ws_size,
                              hipStream_t stream) {
    const float* beta  = (const float*)d_in[0];
    const float* embed = (const float*)d_in[1];
    const int* sid     = (const int*)d_in[2];
    const int* is_cp   = (const int*)d_in[3];
    float* out = (float*)d_out;

    const int N = 65536;                  // per reference setup
    const int B = in_sizes[0] / N;        // beta is (B,N,1) -> B*N elements
    const int D = 256;                    // in_sizes[1] / in_sizes[0]
    (void)D; (void)n_in; (void)out_size; (void)ws_size;

    // workspace carve-up
    char* ws = (char*)d_ws;
    int*   first_cp  = (int*)(ws + 0);
    float* seg_sum   = (float*)(ws + 4096);
    int*   seg_cnt   = (int*)(ws + 8192);
    float* pos_sum   = (float*)(ws + 12288);
    float* neg_sum   = (float*)(ws + 12352);
    float* rep_sum   = (float*)(ws + 12416);
    int*   cpv_cnt   = (int*)(ws + 12480);
    int*   noncp_cnt = (int*)(ws + 12544);
    int*   valid_cnt = (int*)(ws + 12608);
    float* cp_emb    = (float*)(ws + 12800);   // B*K_INST*256 floats

    init_kernel<<<dim3((B * K_INST + 255) / 256), dim3(256), 0, stream>>>(
        first_cp, seg_sum, seg_cnt, pos_sum, neg_sum, rep_sum,
        cpv_cnt, noncp_cnt, valid_cnt, N, B);

    stats_kernel<<<dim3(N / 256, B), dim3(256), 0, stream>>>(
        beta, sid, is_cp, first_cp, pos_sum, neg_sum,
        cpv_cnt, noncp_cnt, valid_cnt, N);

    gather_kernel<<<dim3(K_INST, B), dim3(64), 0, stream>>>(
        embed, first_cp, cp_emb, N);

    const int blocks_per_batch = 1024;
    attraction_kernel<<<dim3(blocks_per_batch, B), dim3(256), 0, stream>>>(
        embed, sid, first_cp, cp_emb, seg_sum, seg_cnt, N, blocks_per_batch);

    repulsion_kernel<<<dim3(K_INST, B), dim3(256), 0, stream>>>(
        cp_emb, first_cp, rep_sum, N);

    final_kernel<<<dim3(1), dim3(256), 0, stream>>>(
        first_cp, seg_sum, seg_cnt, pos_sum, neg_sum, rep_sum,
        cpv_cnt, noncp_cnt, valid_cnt, out, N, B);
}

// Round 2
// 119.988 us; speedup vs baseline: 1.3601x; 1.3601x over previous
//
#include <hip/hip_runtime.h>
#include <math.h>

#define K_INST 256
#define ATTRACTION_W 1.0f
#define REPULSION_W 1.0f
#define BETA_POS_W 1.0f
#define BETA_NEG_W 0.5f

__device__ inline float softplusf(float x) {
    return fmaxf(x, 0.f) + log1pf(expf(-fabsf(x)));
}

__device__ inline float waveReduceSumF(float v) {
    for (int o = 32; o; o >>= 1) v += __shfl_xor(v, o);
    return v;
}
__device__ inline int waveReduceSumI(int v) {
    for (int o = 32; o; o >>= 1) v += __shfl_xor(v, o);
    return v;
}

__global__ void init_kernel(int* first_cp, float* seg_sum, int* seg_cnt,
                            float* pos_sum, float* neg_sum, float* rep_sum,
                            int* cpv_cnt, int* noncp_cnt, int* valid_cnt,
                            int N, int B) {
    int idx = blockIdx.x * blockDim.x + threadIdx.x;
    if (idx < B * K_INST) {
        first_cp[idx] = N;
        seg_sum[idx] = 0.f;
        seg_cnt[idx] = 0;
    }
    if (idx < B) {
        pos_sum[idx] = 0.f; neg_sum[idx] = 0.f; rep_sum[idx] = 0.f;
        cpv_cnt[idx] = 0; noncp_cnt[idx] = 0; valid_cnt[idx] = 0;
    }
}

// 4 points per thread, vectorized loads. grid (N/1024, B), block 256.
__global__ void stats_kernel(const float* __restrict__ beta,
                             const int* __restrict__ sid,
                             const int* __restrict__ is_cp,
                             int* first_cp,
                             float* pos_sum, float* neg_sum,
                             int* cpv_cnt, int* noncp_cnt, int* valid_cnt,
                             int N) {
    int b = blockIdx.y;
    int base = (blockIdx.x * blockDim.x + threadIdx.x) * 4;
    const float* betaB = beta + (size_t)b * N;
    const int* sidB = sid + (size_t)b * N;
    const int* cpB = is_cp + (size_t)b * N;

    float pos = 0.f, neg = 0.f;
    int c_cpv = 0, c_non = 0, c_val = 0;

    int4 s4 = *(const int4*)(sidB + base);
    int4 c4 = *(const int4*)(cpB + base);
    float4 x4 = *(const float4*)(betaB + base);
    int ss[4] = {s4.x, s4.y, s4.z, s4.w};
    int cc[4] = {c4.x, c4.y, c4.z, c4.w};
    float xx[4] = {x4.x, x4.y, x4.z, x4.w};
    #pragma unroll
    for (int e = 0; e < 4; ++e) {
        bool valid = ss[e] >= 0;
        bool cpv = cc[e] && valid;
        if (cpv) {
            pos += softplusf(-xx[e]);
            c_cpv++;
            atomicMin(&first_cp[b * K_INST + ss[e]], base + e);
        }
        if (!cc[e]) {
            neg += softplusf(xx[e]);
            c_non++;
        }
        c_val += valid ? 1 : 0;
    }

    __shared__ float sf[2][4];
    __shared__ int si[3][4];
    pos = waveReduceSumF(pos);
    neg = waveReduceSumF(neg);
    c_cpv = waveReduceSumI(c_cpv);
    c_non = waveReduceSumI(c_non);
    c_val = waveReduceSumI(c_val);
    int wave = threadIdx.x >> 6, lane = threadIdx.x & 63;
    if (lane == 0) {
        sf[0][wave] = pos; sf[1][wave] = neg;
        si[0][wave] = c_cpv; si[1][wave] = c_non; si[2][wave] = c_val;
    }
    __syncthreads();
    if (threadIdx.x == 0) {
        float p = sf[0][0] + sf[0][1] + sf[0][2] + sf[0][3];
        float n = sf[1][0] + sf[1][1] + sf[1][2] + sf[1][3];
        int a = si[0][0] + si[0][1] + si[0][2] + si[0][3];
        int c = si[1][0] + si[1][1] + si[1][2] + si[1][3];
        int v = si[2][0] + si[2][1] + si[2][2] + si[2][3];
        if (p != 0.f) atomicAdd(&pos_sum[b], p);
        if (n != 0.f) atomicAdd(&neg_sum[b], n);
        if (a) atomicAdd(&cpv_cnt[b], a);
        if (c) atomicAdd(&noncp_cnt[b], c);
        if (v) atomicAdd(&valid_cnt[b], v);
    }
}

// gather + transpose fused. grid (K_INST/64, B), block 256.
// writes cp_emb (row-major) and cp_embT (dim-major, for repulsion)
__global__ void gather_kernel(const float* __restrict__ embed,
                              const int* __restrict__ first_cp,
                              float* __restrict__ cp_emb,
                              float* __restrict__ cp_embT, int N) {
    int b = blockIdx.y;
    int k0 = blockIdx.x * 64;
    __shared__ float tile[64][257];
    const float* embB = embed + (size_t)b * N * 256;
    const int* fcB = first_cp + b * K_INST;

    int r = threadIdx.x >> 2;   // row 0..63
    int q = threadIdx.x & 3;    // quarter of the row
    int src = fcB[k0 + r];
    if (src >= N) src = N - 1;
    const float4* srow = (const float4*)(embB + (size_t)src * 256);
    float4* drow = (float4*)(cp_emb + ((size_t)b * K_INST + k0 + r) * 256);
    #pragma unroll
    for (int c = 0; c < 16; ++c) {
        float4 v = srow[q * 16 + c];
        drow[q * 16 + c] = v;
        int col = q * 64 + c * 4;
        tile[r][col + 0] = v.x;
        tile[r][col + 1] = v.y;
        tile[r][col + 2] = v.z;
        tile[r][col + 3] = v.w;
    }
    __syncthreads();
    int kk = threadIdx.x & 63;
    int dg = threadIdx.x >> 6;
    float* T = cp_embT + (size_t)b * K_INST * 256;
    #pragma unroll
    for (int dd = 0; dd < 64; ++dd) {
        int d = dg * 64 + dd;
        T[(size_t)d * 256 + k0 + kk] = tile[kk][d];
    }
}

// attraction: one wave per 8 points per iteration -> 8 loads in flight.
// grid (512, B), block 256 (2048 blocks total = full residency at 8 blk/CU)
__global__ void attraction_kernel(const float* __restrict__ embed,
                                  const int* __restrict__ sid,
                                  const int* __restrict__ first_cp,
                                  const float* __restrict__ cp_emb,
                                  float* seg_sum, int* seg_cnt,
                                  int N, int blocks_per_batch) {
    int b = blockIdx.y;
    __shared__ float s_sum[K_INST];
    __shared__ int s_cnt[K_INST];
    for (int k = threadIdx.x; k < K_INST; k += blockDim.x) { s_sum[k] = 0.f; s_cnt[k] = 0; }
    __syncthreads();

    int wave = threadIdx.x >> 6;
    int lane = threadIdx.x & 63;
    int waves_per_batch = blocks_per_batch * 4;
    int wid = blockIdx.x * 4 + wave;
    int stride = waves_per_batch * 8;

    const float* embB = embed + (size_t)b * N * 256;
    const float* cpB  = cp_emb + (size_t)b * K_INST * 256;
    const int* sidB   = sid + (size_t)b * N;
    const int* fcB    = first_cp + b * K_INST;

    for (int i = wid * 8; i < N; i += stride) {
        int4 sa = *(const int4*)(sidB + i);
        int4 sb = *(const int4*)(sidB + i + 4);
        int ss[8] = {sa.x, sa.y, sa.z, sa.w, sb.x, sb.y, sb.z, sb.w};

        float4 e[8];
        #pragma unroll
        for (int j = 0; j < 8; ++j)
            e[j] = *(const float4*)(embB + (size_t)(i + j) * 256 + lane * 4);

        float v[8];
        unsigned act = 0;
        #pragma unroll
        for (int j = 0; j < 8; ++j) {
            v[j] = 0.f;
            int s = ss[j];
            if (s >= 0 && fcB[s] < N) {
                act |= (1u << j);
                float4 c = *(const float4*)(cpB + (size_t)s * 256 + lane * 4);
                float d0 = e[j].x - c.x, d1 = e[j].y - c.y;
                float d2 = e[j].z - c.z, d3 = e[j].w - c.w;
                v[j] = d0 * d0 + d1 * d1 + d2 * d2 + d3 * d3;
            }
        }
        #pragma unroll
        for (int j = 0; j < 8; ++j) v[j] = waveReduceSumF(v[j]);
        if (lane == 0) {
            #pragma unroll
            for (int j = 0; j < 8; ++j) {
                if (act & (1u << j)) {
                    atomicAdd(&s_sum[ss[j]], v[j]);
                    atomicAdd(&s_cnt[ss[j]], 1);
                }
            }
        }
    }
    __syncthreads();
    for (int k = threadIdx.x; k < K_INST; k += blockDim.x) {
        if (s_cnt[k]) {
            atomicAdd(&seg_sum[b * K_INST + k], s_sum[k]);
            atomicAdd(&seg_cnt[b * K_INST + k], s_cnt[k]);
        }
    }
}

// repulsion from transposed table: coalesced. grid (K_INST/8, B), block 256.
__global__ void repulsion_kernel(const float* __restrict__ cp_emb,
                                 const float* __restrict__ cp_embT,
                                 const int* __restrict__ first_cp,
                                 float* rep_sum, int N) {
    int b = blockIdx.y;
    int i0 = blockIdx.x * 8;
    __shared__ float srow[8][260];
    const float* cpB = cp_emb + (size_t)b * K_INST * 256;
    const float* T = cp_embT + (size_t)b * K_INST * 256;

    {   // load 8 i-rows coalesced: 32 threads/row, 8 floats each
        int r = threadIdx.x >> 5, cc = (threadIdx.x & 31) * 8;
        float4 a = *(const float4*)(cpB + (size_t)(i0 + r) * 256 + cc);
        float4 bv = *(const float4*)(cpB + (size_t)(i0 + r) * 256 + cc + 4);
        srow[r][cc + 0] = a.x;  srow[r][cc + 1] = a.y;
        srow[r][cc + 2] = a.z;  srow[r][cc + 3] = a.w;
        srow[r][cc + 4] = bv.x; srow[r][cc + 5] = bv.y;
        srow[r][cc + 6] = bv.z; srow[r][cc + 7] = bv.w;
    }
    __syncthreads();

    int j = threadIdx.x;
    bool has_j = first_cp[b * K_INST + j] < N;
    float acc[8] = {0.f, 0.f, 0.f, 0.f, 0.f, 0.f, 0.f, 0.f};
    for (int d = 0; d < 256; d += 2) {
        float v0 = T[(size_t)d * 256 + j];
        float v1 = T[(size_t)(d + 1) * 256 + j];
        #pragma unroll
        for (int r = 0; r < 8; ++r) {
            float f0 = srow[r][d] - v0;
            float f1 = srow[r][d + 1] - v1;
            acc[r] += f0 * f0 + f1 * f1;
        }
    }
    float val = 0.f;
    #pragma unroll
    for (int r = 0; r < 8; ++r) {
        bool has_i = first_cp[b * K_INST + i0 + r] < N;
        if (has_i && has_j) val += expf(-acc[r]);
    }
    __shared__ float sf[4];
    val = waveReduceSumF(val);
    int wave = threadIdx.x >> 6, lane = threadIdx.x & 63;
    if (lane == 0) sf[wave] = val;
    __syncthreads();
    if (threadIdx.x == 0) {
        atomicAdd(&rep_sum[b], sf[0] + sf[1] + sf[2] + sf[3]);
    }
}

__global__ void final_kernel(const int* __restrict__ first_cp,
                             const float* __restrict__ seg_sum,
                             const int* __restrict__ seg_cnt,
                             const float* __restrict__ pos_sum,
                             const float* __restrict__ neg_sum,
                             const float* __restrict__ rep_sum,
                             const int* __restrict__ cpv_cnt,
                             const int* __restrict__ noncp_cnt,
                             const int* __restrict__ valid_cnt,
                             float* out, int N, int B) {
    __shared__ float s_att[4];
    __shared__ int s_m[4];
    float loss_sum = 0.f;
    int ok_cnt = 0;
    int wave = threadIdx.x >> 6, lane = threadIdx.x & 63;
    for (int b = 0; b < B; ++b) {
        int k = threadIdx.x;
        int fc = first_cp[b * K_INST + k];
        int has = (fc < N) ? 1 : 0;
        int cnt = seg_cnt[b * K_INST + k];
        float att = (cnt > 0) ? (seg_sum[b * K_INST + k] / (float)cnt) : 0.f;
        att = waveReduceSumF(att);
        has = waveReduceSumI(has);
        if (lane == 0) { s_att[wave] = att; s_m[wave] = has; }
        __syncthreads();
        if (threadIdx.x == 0) {
            float attraction = (s_att[0] + s_att[1] + s_att[2] + s_att[3]) * ATTRACTION_W;
            int M = s_m[0] + s_m[1] + s_m[2] + s_m[3];
            float pos = pos_sum[b] / fmaxf((float)cpv_cnt[b], 1.f);
            float neg = neg_sum[b] / fmaxf((float)noncp_cnt[b], 1.f);
            float beta_loss = BETA_POS_W * pos + BETA_NEG_W * neg;
            float rep = 0.f;
            if (M > 1) {
                float mm = (float)M * (float)M;
                rep = (rep_sum[b] / fmaxf(mm, 1.f)) * REPULSION_W;
            }
            float loss = beta_loss + attraction + rep;
            bool ok = (valid_cnt[b] > 0) && (cpv_cnt[b] > 0);
            if (ok) { loss_sum += loss; ok_cnt += 1; }
        }
        __syncthreads();
    }
    if (threadIdx.x == 0) {
        out[0] = (ok_cnt > 0) ? (loss_sum / (float)ok_cnt) : 0.f;
    }
}

extern "C" void kernel_launch(void* const* d_in, const int* in_sizes, int n_in,
                              void* d_out, int out_size, void* d_ws, size_t ws_size,
                              hipStream_t stream) {
    const float* beta  = (const float*)d_in[0];
    const float* embed = (const float*)d_in[1];
    const int* sid     = (const int*)d_in[2];
    const int* is_cp   = (const int*)d_in[3];
    float* out = (float*)d_out;

    const int N = 65536;
    const int B = in_sizes[0] / N;
    (void)n_in; (void)out_size; (void)ws_size;

    char* ws = (char*)d_ws;
    int*   first_cp  = (int*)(ws + 0);
    float* seg_sum   = (float*)(ws + 4096);
    int*   seg_cnt   = (int*)(ws + 8192);
    float* pos_sum   = (float*)(ws + 12288);
    float* neg_sum   = (float*)(ws + 12352);
    float* rep_sum   = (float*)(ws + 12416);
    int*   cpv_cnt   = (int*)(ws + 12480);
    int*   noncp_cnt = (int*)(ws + 12544);
    int*   valid_cnt = (int*)(ws + 12608);
    float* cp_emb    = (float*)(ws + 16384);                       // B*K*256 f32 (1 MiB @ B=4)
    float* cp_embT   = (float*)(ws + 16384 + (size_t)B * K_INST * 256 * 4);

    init_kernel<<<dim3((B * K_INST + 255) / 256), dim3(256), 0, stream>>>(
        first_cp, seg_sum, seg_cnt, pos_sum, neg_sum, rep_sum,
        cpv_cnt, noncp_cnt, valid_cnt, N, B);

    stats_kernel<<<dim3(N / 1024, B), dim3(256), 0, stream>>>(
        beta, sid, is_cp, first_cp, pos_sum, neg_sum,
        cpv_cnt, noncp_cnt, valid_cnt, N);

    gather_kernel<<<dim3(K_INST / 64, B), dim3(256), 0, stream>>>(
        embed, first_cp, cp_emb, cp_embT, N);

    const int blocks_per_batch = 512;
    attraction_kernel<<<dim3(blocks_per_batch, B), dim3(256), 0, stream>>>(
        embed, sid, first_cp, cp_emb, seg_sum, seg_cnt, N, blocks_per_batch);

    repulsion_kernel<<<dim3(K_INST / 8, B), dim3(256), 0, stream>>>(
        cp_emb, cp_embT, first_cp, rep_sum, N);

    final_kernel<<<dim3(1), dim3(256), 0, stream>>>(
        first_cp, seg_sum, seg_cnt, pos_sum, neg_sum, rep_sum,
        cpv_cnt, noncp_cnt, valid_cnt, out, N, B);
}

// Round 3
// 103.088 us; speedup vs baseline: 1.5831x; 1.1639x over previous
//
#include <hip/hip_runtime.h>
#include <math.h>

#define K_INST 256
#define ATTRACTION_W 1.0f
#define REPULSION_W 1.0f
#define BETA_POS_W 1.0f
#define BETA_NEG_W 0.5f

__device__ inline float softplusf(float x) {
    return fmaxf(x, 0.f) + log1pf(expf(-fabsf(x)));
}

__device__ inline float waveReduceSumF(float v) {
    for (int o = 32; o; o >>= 1) v += __shfl_xor(v, o);
    return v;
}
__device__ inline int waveReduceSumI(int v) {
    for (int o = 32; o; o >>= 1) v += __shfl_xor(v, o);
    return v;
}

__global__ void init_kernel(int* first_cp, float* seg_sum, int* seg_cnt,
                            float* pos_sum, float* neg_sum, float* rep_sum,
                            int* cpv_cnt, int* noncp_cnt, int* valid_cnt,
                            int N, int B) {
    int idx = blockIdx.x * blockDim.x + threadIdx.x;
    if (idx < B * K_INST) {
        first_cp[idx] = N;
        seg_sum[idx] = 0.f;
        seg_cnt[idx] = 0;
    }
    if (idx < B) {
        pos_sum[idx] = 0.f; neg_sum[idx] = 0.f; rep_sum[idx] = 0.f;
        cpv_cnt[idx] = 0; noncp_cnt[idx] = 0; valid_cnt[idx] = 0;
    }
}

// 1 point per thread. grid (N/256, B), block 256.
__global__ void stats_kernel(const float* __restrict__ beta,
                             const int* __restrict__ sid,
                             const int* __restrict__ is_cp,
                             int* first_cp,
                             float* pos_sum, float* neg_sum,
                             int* cpv_cnt, int* noncp_cnt, int* valid_cnt,
                             int N) {
    int b = blockIdx.y;
    int i = blockIdx.x * blockDim.x + threadIdx.x;
    size_t gi = (size_t)b * N + i;
    int s = sid[gi];
    int cp = is_cp[gi];
    float x = beta[gi];

    bool valid = s >= 0;
    bool cpv = cp && valid;
    float pos = 0.f, neg = 0.f;
    int c_cpv = 0, c_non = 0, c_val = valid ? 1 : 0;
    if (cpv) {
        pos = softplusf(-x);
        c_cpv = 1;
        atomicMin(&first_cp[b * K_INST + s], i);
    }
    if (!cp) {
        neg = softplusf(x);
        c_non = 1;
    }

    __shared__ float sf[2][4];
    __shared__ int si[3][4];
    pos = waveReduceSumF(pos);
    neg = waveReduceSumF(neg);
    c_cpv = waveReduceSumI(c_cpv);
    c_non = waveReduceSumI(c_non);
    c_val = waveReduceSumI(c_val);
    int wave = threadIdx.x >> 6, lane = threadIdx.x & 63;
    if (lane == 0) {
        sf[0][wave] = pos; sf[1][wave] = neg;
        si[0][wave] = c_cpv; si[1][wave] = c_non; si[2][wave] = c_val;
    }
    __syncthreads();
    if (threadIdx.x == 0) {
        float p = sf[0][0] + sf[0][1] + sf[0][2] + sf[0][3];
        float n = sf[1][0] + sf[1][1] + sf[1][2] + sf[1][3];
        int a = si[0][0] + si[0][1] + si[0][2] + si[0][3];
        int c = si[1][0] + si[1][1] + si[1][2] + si[1][3];
        int v = si[2][0] + si[2][1] + si[2][2] + si[2][3];
        if (p != 0.f) atomicAdd(&pos_sum[b], p);
        if (n != 0.f) atomicAdd(&neg_sum[b], n);
        if (a) atomicAdd(&cpv_cnt[b], a);
        if (c) atomicAdd(&noncp_cnt[b], c);
        if (v) atomicAdd(&valid_cnt[b], v);
    }
}

// one block per (k, b), 64 threads. writes row + transposed scatter.
__global__ void gather_kernel(const float* __restrict__ embed,
                              const int* __restrict__ first_cp,
                              float* __restrict__ cp_emb,
                              float* __restrict__ cp_embT, int N) {
    int b = blockIdx.y;
    int k = blockIdx.x;
    int src = first_cp[b * K_INST + k];
    if (src >= N) src = N - 1;
    int lane = threadIdx.x;  // 0..63
    const float* embB = embed + (size_t)b * N * 256;
    float4 v = ((const float4*)(embB + (size_t)src * 256))[lane];
    ((float4*)(cp_emb + ((size_t)b * K_INST + k) * 256))[lane] = v;
    float* T = cp_embT + (size_t)b * K_INST * 256;
    int d = lane * 4;
    T[(size_t)(d + 0) * 256 + k] = v.x;
    T[(size_t)(d + 1) * 256 + k] = v.y;
    T[(size_t)(d + 2) * 256 + k] = v.z;
    T[(size_t)(d + 3) * 256 + k] = v.w;
}

// fused: blockIdx.x < 32 -> repulsion (8 i-rows each); else attraction.
// grid (32 + atr_blocks, B), block 256.
__global__ void attraction_repulsion_kernel(
        const float* __restrict__ embed,
        const int* __restrict__ sid,
        const int* __restrict__ first_cp,
        const float* __restrict__ cp_emb,
        const float* __restrict__ cp_embT,
        float* seg_sum, int* seg_cnt, float* rep_sum,
        int N, int atr_blocks) {
    int b = blockIdx.y;
    __shared__ float s_sum[K_INST];
    __shared__ int s_cnt[K_INST];
    __shared__ float srow[8][260];
    __shared__ float sf[4];

    const float* cpB = cp_emb + (size_t)b * K_INST * 256;
    const int* fcB = first_cp + b * K_INST;

    if (blockIdx.x < 32) {
        // ---------------- repulsion ----------------
        int i0 = blockIdx.x * 8;
        const float* T = cp_embT + (size_t)b * K_INST * 256;
        {
            int r = threadIdx.x >> 5, cc = (threadIdx.x & 31) * 8;
            float4 a = *(const float4*)(cpB + (size_t)(i0 + r) * 256 + cc);
            float4 bv = *(const float4*)(cpB + (size_t)(i0 + r) * 256 + cc + 4);
            srow[r][cc + 0] = a.x;  srow[r][cc + 1] = a.y;
            srow[r][cc + 2] = a.z;  srow[r][cc + 3] = a.w;
            srow[r][cc + 4] = bv.x; srow[r][cc + 5] = bv.y;
            srow[r][cc + 6] = bv.z; srow[r][cc + 7] = bv.w;
        }
        __syncthreads();

        int j = threadIdx.x;
        bool has_j = fcB[j] < N;
        float acc[8] = {0.f, 0.f, 0.f, 0.f, 0.f, 0.f, 0.f, 0.f};
        for (int d = 0; d < 256; d += 2) {
            float v0 = T[(size_t)d * 256 + j];
            float v1 = T[(size_t)(d + 1) * 256 + j];
            #pragma unroll
            for (int r = 0; r < 8; ++r) {
                float f0 = srow[r][d] - v0;
                float f1 = srow[r][d + 1] - v1;
                acc[r] += f0 * f0 + f1 * f1;
            }
        }
        float val = 0.f;
        #pragma unroll
        for (int r = 0; r < 8; ++r) {
            bool has_i = fcB[i0 + r] < N;
            if (has_i && has_j) val += expf(-acc[r]);
        }
        val = waveReduceSumF(val);
        int wave = threadIdx.x >> 6, lane = threadIdx.x & 63;
        if (lane == 0) sf[wave] = val;
        __syncthreads();
        if (threadIdx.x == 0)
            atomicAdd(&rep_sum[b], sf[0] + sf[1] + sf[2] + sf[3]);
    } else {
        // ---------------- attraction ----------------
        for (int k = threadIdx.x; k < K_INST; k += blockDim.x) { s_sum[k] = 0.f; s_cnt[k] = 0; }
        __syncthreads();

        int bx = blockIdx.x - 32;
        int wave = threadIdx.x >> 6;
        int lane = threadIdx.x & 63;
        int waves_per_batch = atr_blocks * 4;
        int wid = bx * 4 + wave;
        int stride = waves_per_batch * 8;

        const float* embB = embed + (size_t)b * N * 256;
        const int* sidB = sid + (size_t)b * N;

        for (int i = wid * 8; i < N; i += stride) {
            int4 sa = *(const int4*)(sidB + i);
            int4 sb = *(const int4*)(sidB + i + 4);
            int ss[8] = {sa.x, sa.y, sa.z, sa.w, sb.x, sb.y, sb.z, sb.w};

            // issue all 16 vector loads up front (cp row clamped, unconditional)
            float4 e[8], c[8];
            #pragma unroll
            for (int j = 0; j < 8; ++j)
                e[j] = *(const float4*)(embB + (size_t)(i + j) * 256 + lane * 4);
            #pragma unroll
            for (int j = 0; j < 8; ++j) {
                int sc = ss[j] < 0 ? 0 : ss[j];
                c[j] = *(const float4*)(cpB + (size_t)sc * 256 + lane * 4);
            }

            float v[8];
            #pragma unroll
            for (int j = 0; j < 8; ++j) {
                float d0 = e[j].x - c[j].x, d1 = e[j].y - c[j].y;
                float d2 = e[j].z - c[j].z, d3 = e[j].w - c[j].w;
                v[j] = d0 * d0 + d1 * d1 + d2 * d2 + d3 * d3;
            }
            #pragma unroll
            for (int j = 0; j < 8; ++j) v[j] = waveReduceSumF(v[j]);
            if (lane == 0) {
                #pragma unroll
                for (int j = 0; j < 8; ++j) {
                    int s = ss[j];
                    if (s >= 0 && fcB[s] < N) {
                        atomicAdd(&s_sum[s], v[j]);
                        atomicAdd(&s_cnt[s], 1);
                    }
                }
            }
        }
        __syncthreads();
        for (int k = threadIdx.x; k < K_INST; k += blockDim.x) {
            if (s_cnt[k]) {
                atomicAdd(&seg_sum[b * K_INST + k], s_sum[k]);
                atomicAdd(&seg_cnt[b * K_INST + k], s_cnt[k]);
            }
        }
    }
}

__global__ void final_kernel(const int* __restrict__ first_cp,
                             const float* __restrict__ seg_sum,
                             const int* __restrict__ seg_cnt,
                             const float* __restrict__ pos_sum,
                             const float* __restrict__ neg_sum,
                             const float* __restrict__ rep_sum,
                             const int* __restrict__ cpv_cnt,
                             const int* __restrict__ noncp_cnt,
                             const int* __restrict__ valid_cnt,
                             float* out, int N, int B) {
    __shared__ float s_att[4];
    __shared__ int s_m[4];
    float loss_sum = 0.f;
    int ok_cnt = 0;
    int wave = threadIdx.x >> 6, lane = threadIdx.x & 63;
    for (int b = 0; b < B; ++b) {
        int k = threadIdx.x;
        int fc = first_cp[b * K_INST + k];
        int has = (fc < N) ? 1 : 0;
        int cnt = seg_cnt[b * K_INST + k];
        float att = (cnt > 0) ? (seg_sum[b * K_INST + k] / (float)cnt) : 0.f;
        att = waveReduceSumF(att);
        has = waveReduceSumI(has);
        if (lane == 0) { s_att[wave] = att; s_m[wave] = has; }
        __syncthreads();
        if (threadIdx.x == 0) {
            float attraction = (s_att[0] + s_att[1] + s_att[2] + s_att[3]) * ATTRACTION_W;
            int M = s_m[0] + s_m[1] + s_m[2] + s_m[3];
            float pos = pos_sum[b] / fmaxf((float)cpv_cnt[b], 1.f);
            float neg = neg_sum[b] / fmaxf((float)noncp_cnt[b], 1.f);
            float beta_loss = BETA_POS_W * pos + BETA_NEG_W * neg;
            float rep = 0.f;
            if (M > 1) {
                float mm = (float)M * (float)M;
                rep = (rep_sum[b] / fmaxf(mm, 1.f)) * REPULSION_W;
            }
            float loss = beta_loss + attraction + rep;
            bool ok = (valid_cnt[b] > 0) && (cpv_cnt[b] > 0);
            if (ok) { loss_sum += loss; ok_cnt += 1; }
        }
        __syncthreads();
    }
    if (threadIdx.x == 0) {
        out[0] = (ok_cnt > 0) ? (loss_sum / (float)ok_cnt) : 0.f;
    }
}

extern "C" void kernel_launch(void* const* d_in, const int* in_sizes, int n_in,
                              void* d_out, int out_size, void* d_ws, size_t ws_size,
                              hipStream_t stream) {
    const float* beta  = (const float*)d_in[0];
    const float* embed = (const float*)d_in[1];
    const int* sid     = (const int*)d_in[2];
    const int* is_cp   = (const int*)d_in[3];
    float* out = (float*)d_out;

    const int N = 65536;
    const int B = in_sizes[0] / N;
    (void)n_in; (void)out_size; (void)ws_size;

    char* ws = (char*)d_ws;
    int*   first_cp  = (int*)(ws + 0);
    float* seg_sum   = (float*)(ws + 4096);
    int*   seg_cnt   = (int*)(ws + 8192);
    float* pos_sum   = (float*)(ws + 12288);
    float* neg_sum   = (float*)(ws + 12352);
    float* rep_sum   = (float*)(ws + 12416);
    int*   cpv_cnt   = (int*)(ws + 12480);
    int*   noncp_cnt = (int*)(ws + 12544);
    int*   valid_cnt = (int*)(ws + 12608);
    float* cp_emb    = (float*)(ws + 16384);
    float* cp_embT   = (float*)(ws + 16384 + (size_t)B * K_INST * 256 * 4);

    init_kernel<<<dim3((B * K_INST + 255) / 256), dim3(256), 0, stream>>>(
        first_cp, seg_sum, seg_cnt, pos_sum, neg_sum, rep_sum,
        cpv_cnt, noncp_cnt, valid_cnt, N, B);

    stats_kernel<<<dim3(N / 256, B), dim3(256), 0, stream>>>(
        beta, sid, is_cp, first_cp, pos_sum, neg_sum,
        cpv_cnt, noncp_cnt, valid_cnt, N);

    gather_kernel<<<dim3(K_INST, B), dim3(64), 0, stream>>>(
        embed, first_cp, cp_emb, cp_embT, N);

    const int atr_blocks = 512;
    attraction_repulsion_kernel<<<dim3(32 + atr_blocks, B), dim3(256), 0, stream>>>(
        embed, sid, first_cp, cp_emb, cp_embT,
        seg_sum, seg_cnt, rep_sum, N, atr_blocks);

    final_kernel<<<dim3(1), dim3(256), 0, stream>>>(
        first_cp, seg_sum, seg_cnt, pos_sum, neg_sum, rep_sum,
        cpv_cnt, noncp_cnt, valid_cnt, out, N, B);
}